// Round 11
// baseline (240.125 us; speedup 1.0000x reference)
//
#include <hip/hip_runtime.h>

// KDE entropy loss, MI355X/gfx950 — fp8 fused GEMM, symmetric pairs once,
// wrapped-diagonal mapping. R11: 3 blocks/CU (6 waves/SIMD). Key insight from
// R10: AGPRs count in the unified file (~92 regs/wave -> only 2 blocks fit).
// Fix: sequential j-tiles per iteration -> only ONE f32x16 acc live at a time
// (peak ~80 unified regs), __launch_bounds__(512,6), single 32 KB B buffer,
// grid 128x6 = 768 blocks = 3/CU. Serial stage-wait per iter is covered by
// the other two resident blocks (3-deep TLP).
// ws: [0,4MiB) Xn fp8 [16384][256]; [4MiB,+64KiB) density f32; then ticket u32.

#define NROWS 16384
#define KDIM 256            // bytes per fp8 row
#define NTILE 128
#define NT (NROWS / NTILE)  // 128 tile rows
#define NSTRIP 6
#define TOTAL_BLOCKS (NT * NSTRIP)  // 768 blocks of 512 thr = 3 per CU

// sqrt(5 * log2(e)): folded into both operands -> sim scaled by 5*log2(e),
// so kernel = exp2(sim_scaled) = exp(5*sim).
#define SQRT_KLOG2E 2.68579577857f

typedef int i32x4_t __attribute__((ext_vector_type(4)));
typedef int i32x8_t __attribute__((ext_vector_type(8)));
typedef float f32x16_t __attribute__((ext_vector_type(16)));
typedef __attribute__((address_space(1))) const void global_cvoid_t;
typedef __attribute__((address_space(3))) void lds_void_t;

#if __has_builtin(__builtin_amdgcn_exp2f)
#define EXP2(x) __builtin_amdgcn_exp2f(x)
#else
#define EXP2(x) exp2f(x)
#endif

union frag8 { i32x8_t v8; i32x4_t v4[2]; };

// One wave per row: sqrt(5log2e)/max(||x||,eps), fp8 e4m3 out; zero density+ticket.
__global__ __launch_bounds__(256)
void kde_normalize(const float* __restrict__ X, unsigned int* __restrict__ Xn8,
                   float* __restrict__ density, unsigned int* __restrict__ ticket) {
  const int wave = threadIdx.x >> 6;
  const int lane = threadIdx.x & 63;
  const int row = blockIdx.x * 4 + wave;
  const float4 v = ((const float4*)(X + (size_t)row * KDIM))[lane];
  float ss = v.x * v.x + v.y * v.y + v.z * v.z + v.w * v.w;
  ss += __shfl_xor(ss, 1);
  ss += __shfl_xor(ss, 2);
  ss += __shfl_xor(ss, 4);
  ss += __shfl_xor(ss, 8);
  ss += __shfl_xor(ss, 16);
  ss += __shfl_xor(ss, 32);
  const float scale = SQRT_KLOG2E / fmaxf(sqrtf(ss), 1e-12f);
  int p = 0;
  p = __builtin_amdgcn_cvt_pk_fp8_f32(v.x * scale, v.y * scale, p, false);
  p = __builtin_amdgcn_cvt_pk_fp8_f32(v.z * scale, v.w * scale, p, true);
  Xn8[(size_t)row * 64 + lane] = (unsigned int)p;
  if (threadIdx.x < 4) density[blockIdx.x * 4 + threadIdx.x] = 0.0f;
  if (blockIdx.x == 0 && threadIdx.x == 0) *ticket = 0u;
}

// Block (bi, s): row tile bi; J = (bi+t) mod 128, t in the strip
// s<4: t0=11s, 11 tiles; s=4: t0=44, 10; s=5: t0=54, 10.
// Extra t=64 goes to s==0 (bi<64) — y=0 dispatches first, no tail.
// Each unordered tile pair once. 8 waves 4x2 over 128x128; wave = 32x64 as
// TWO SEQUENTIAL 32x32x64 fp8 MFMA tiles (scale=1 -> exact e4m3), so only
// one 16-reg accumulator is live at a time.
__global__ __launch_bounds__(512, 6)
void kde_gemm(const unsigned char* __restrict__ Xn8, float* __restrict__ density,
              unsigned int* __restrict__ ticket, float* __restrict__ out) {
  extern __shared__ char smem[];
  char* buf = smem;  // 32 KB single B buffer (also carries A at entry)

  const int tid = threadIdx.x;
  const int wave = tid >> 6;   // 0..7
  const int lane = tid & 63;
  const int wr = wave >> 1;    // row quarter 0..3 (32 rows each)
  const int wc = wave & 1;     // col half 0..1 (64 cols each)
  const int m32 = lane & 31;
  const int h = lane >> 5;
  const int bi = blockIdx.x;
  const int s = blockIdx.y;
  const int t0 = (s < 4) ? s * 11 : 44 + (s - 4) * 10;
  const int nt = ((s < 4) ? 11 : 10) + ((s == 0 && bi < NT / 2) ? 1 : 0);
  const char* Xb = (const char*)Xn8;

  // Chunk c = rt*8 + kb*2 + hh: lane holds M[rt*32+m32][kb*64+h*32+hh*16 ..+15].
#define STAGE(base_row)                                                           \
  for (int c = wave; c < 32; c += 8) {                                            \
    const int rt = c >> 3, kb = (c >> 1) & 3, hh = c & 1;                         \
    const size_t gofs =                                                           \
        (size_t)((base_row) + rt * 32 + m32) * KDIM + kb * 64 + h * 32 + hh * 16; \
    __builtin_amdgcn_global_load_lds((global_cvoid_t*)(Xb + gofs),                \
                                     (lds_void_t*)(buf + c * 1024), 16, 0, 0);    \
  }

  // A tile through the buffer into registers (reused across all nt J-tiles).
  STAGE(bi * NTILE);
  __syncthreads();  // A landed
  frag8 areg[4];
#pragma unroll
  for (int kb = 0; kb < 4; kb++) {
    const char* pa = buf + (wr * 8 + kb * 2) * 1024 + lane * 16;
    areg[kb].v4[0] = *(const i32x4_t*)pa;
    areg[kb].v4[1] = *(const i32x4_t*)(pa + 1024);
  }
  __syncthreads();  // all waves done reading A from buf

  float rs[16];
#pragma unroll
  for (int r = 0; r < 16; r++) rs[r] = 0.0f;

  for (int k = 0; k < nt; ++k) {
    const int t = (k == 11) ? 64 : t0 + k;   // k==11 only on s==0, bi<64
    const int J = (bi + t) & (NT - 1);

    STAGE(J * NTILE);
    __syncthreads();  // B(k) landed (own staging vmcnt + prior atomic acks)

    // Two j-tiles SEQUENTIALLY: one acc live at a time (register budget).
#pragma unroll
    for (int j = 0; j < 2; ++j) {
      f32x16_t acc = (f32x16_t)0.0f;
#pragma unroll
      for (int kb = 0; kb < 4; ++kb) {
        frag8 bf;
        const char* pb = buf + ((wc * 2 + j) * 8 + kb * 2) * 1024 + lane * 16;
        bf.v4[0] = *(const i32x4_t*)pb;
        bf.v4[1] = *(const i32x4_t*)(pb + 1024);
        acc = __builtin_amdgcn_mfma_scale_f32_32x32x64_f8f6f4(
            areg[kb].v8, bf.v8, acc, 0, 0, 0, 127, 0, 127);
      }
      // Epilogue: e = exp2(sim_scaled) = exp(5*sim). rowsums in regs across
      // k and j (same 32 rows for both j). C/D: col=m32, row=(r&3)+8*(r>>2)+4*h.
      float c = 0.0f;
#pragma unroll
      for (int r = 0; r < 16; r++) {
        const float e = EXP2(acc[r]);
        rs[r] += e;
        c += e;
      }
      if (t != 0) {  // diagonal tile (t=0): rowsum only
        c += __shfl_xor(c, 32);  // combine h halves -> 32-row column partial
        if (h == 0)              // 4 atomics/col across wr waves
          atomicAdd(&density[J * NTILE + wc * 64 + j * 32 + m32], c);
      }
    }

    __syncthreads();  // all waves done reading buf; safe to restage
  }

  // Row epilogue: reduce over 32 cols (m32), scatter; 2 atomics/row (wc=0,1).
#pragma unroll
  for (int r = 0; r < 16; r++) {
    float v = rs[r];
    v += __shfl_xor(v, 1);
    v += __shfl_xor(v, 2);
    v += __shfl_xor(v, 4);
    v += __shfl_xor(v, 8);
    v += __shfl_xor(v, 16);
    if (m32 == 0) {
      const int row = bi * NTILE + wr * 32 + (r & 3) + 8 * (r >> 2) + 4 * h;
      atomicAdd(&density[row], v);
    }
  }
#undef STAGE

  // Ticket: last finished block computes the entropy (saves 2 launches).
  __syncthreads();  // all waves' atomics issued & drained; buf free
  if (tid == 0) {
    __threadfence();
    ((volatile unsigned int*)smem)[0] = atomicAdd(ticket, 1u);
  }
  __syncthreads();
  if (((volatile unsigned int*)smem)[0] == TOTAL_BLOCKS - 1) {
    __threadfence();
    float ssum = 0.0f;
    for (int i = tid; i < NROWS; i += 512) {
      const float d = __hip_atomic_load(&density[i], __ATOMIC_RELAXED,
                                        __HIP_MEMORY_SCOPE_AGENT);
      ssum += logf(d + 1e-9f);
    }
    ssum += __shfl_xor(ssum, 1);
    ssum += __shfl_xor(ssum, 2);
    ssum += __shfl_xor(ssum, 4);
    ssum += __shfl_xor(ssum, 8);
    ssum += __shfl_xor(ssum, 16);
    ssum += __shfl_xor(ssum, 32);
    float* red = ((float*)smem) + 16;
    if (lane == 0) red[wave] = ssum;
    __syncthreads();
    if (tid == 0) {
      float tot = 0.0f;
      for (int w = 0; w < 8; w++) tot += red[w];
      out[0] = -tot / (float)NROWS;
    }
  }
}

extern "C" void kernel_launch(void* const* d_in, const int* in_sizes, int n_in,
                              void* d_out, int out_size, void* d_ws, size_t ws_size,
                              hipStream_t stream) {
  const float* X = (const float*)d_in[0];
  float* out = (float*)d_out;
  char* ws = (char*)d_ws;
  unsigned int* Xn8 = (unsigned int*)ws;
  float* density = (float*)(ws + (size_t)NROWS * KDIM);
  unsigned int* ticket = (unsigned int*)(density + NROWS);

  hipFuncSetAttribute((const void*)kde_gemm,
                      hipFuncAttributeMaxDynamicSharedMemorySize, 32768);

  kde_normalize<<<NROWS / 4, 256, 0, stream>>>(X, Xn8, density, ticket);
  kde_gemm<<<dim3(NT, NSTRIP), 512, 32768, stream>>>((const unsigned char*)ws,
                                                     density, ticket, out);
}

// Round 12
// 142.804 us; speedup vs baseline: 1.6815x; 1.6815x over previous
//
#include <hip/hip_runtime.h>

// KDE entropy loss, MI355X/gfx950 — fp8 fused GEMM, symmetric pairs once.
// R12: 256x128 block tiles — two 128-row tile groups (I0=2bi: waves 0-3,
// I1=2bi+1: waves 4-7) share each staged B(J) tile: 16 MFMA/wave per barrier
// (2x R7), half the staging + barriers per unit MFMA. Registers identical to
// R7 (areg 32 + acc[2] + rs[16], (512,4) budget — proven no-spill), 64 KB
// LDS dbuf, 2 blocks/CU (4 waves/SIMD — the measured TLP ceiling: 6 spills).
// Wrapped diagonal: J=(2bi+t)&127; g0 active t<=tmax0, g1 active 1<=t<=tmax1+1;
// diag (rowsum-only) at t=0 (g0) / t=1 (g1); wrap tiles only for I<64.
// ws: [0,4MiB) Xn fp8 [16384][256]; [4MiB,+64KiB) density f32; then ticket u32.

#define NROWS 16384
#define KDIM 256            // bytes per fp8 row
#define NT 128              // 128-row tiles
#define NSTRIP 8
#define TOTAL_BLOCKS (64 * NSTRIP)  // 512 blocks of 512 thr = 2 per CU

// sqrt(5 * log2(e)): folded into both operands -> sim scaled by 5*log2(e),
// so kernel = exp2(sim_scaled) = exp(5*sim).
#define SQRT_KLOG2E 2.68579577857f

typedef int i32x4_t __attribute__((ext_vector_type(4)));
typedef int i32x8_t __attribute__((ext_vector_type(8)));
typedef float f32x16_t __attribute__((ext_vector_type(16)));
typedef __attribute__((address_space(1))) const void global_cvoid_t;
typedef __attribute__((address_space(3))) void lds_void_t;

#if __has_builtin(__builtin_amdgcn_exp2f)
#define EXP2(x) __builtin_amdgcn_exp2f(x)
#else
#define EXP2(x) exp2f(x)
#endif

union frag8 { i32x8_t v8; i32x4_t v4[2]; };

// One wave per row: sqrt(5log2e)/max(||x||,eps), fp8 e4m3 out; zero density+ticket.
__global__ __launch_bounds__(256)
void kde_normalize(const float* __restrict__ X, unsigned int* __restrict__ Xn8,
                   float* __restrict__ density, unsigned int* __restrict__ ticket) {
  const int wave = threadIdx.x >> 6;
  const int lane = threadIdx.x & 63;
  const int row = blockIdx.x * 4 + wave;
  const float4 v = ((const float4*)(X + (size_t)row * KDIM))[lane];
  float ss = v.x * v.x + v.y * v.y + v.z * v.z + v.w * v.w;
  ss += __shfl_xor(ss, 1);
  ss += __shfl_xor(ss, 2);
  ss += __shfl_xor(ss, 4);
  ss += __shfl_xor(ss, 8);
  ss += __shfl_xor(ss, 16);
  ss += __shfl_xor(ss, 32);
  const float scale = SQRT_KLOG2E / fmaxf(sqrtf(ss), 1e-12f);
  int p = 0;
  p = __builtin_amdgcn_cvt_pk_fp8_f32(v.x * scale, v.y * scale, p, false);
  p = __builtin_amdgcn_cvt_pk_fp8_f32(v.z * scale, v.w * scale, p, true);
  Xn8[(size_t)row * 64 + lane] = (unsigned int)p;
  if (threadIdx.x < 4) density[blockIdx.x * 4 + threadIdx.x] = 0.0f;
  if (blockIdx.x == 0 && threadIdx.x == 0) *ticket = 0u;
}

__global__ __launch_bounds__(512, 4)
void kde_gemm(const unsigned char* __restrict__ Xn8, float* __restrict__ density,
              unsigned int* __restrict__ ticket, float* __restrict__ out) {
  extern __shared__ char smem[];
  char* buf0 = smem;           // 32 KB
  char* buf1 = smem + 32768;   // 32 KB

  const int tid = threadIdx.x;
  const int wave = tid >> 6;   // 0..7
  const int lane = tid & 63;
  const int g = wave >> 2;     // row group: 0 -> tile 2bi, 1 -> tile 2bi+1
  const int wr2 = wave & 3;    // row quarter within the 128-tile (32 rows)
  const int m32 = lane & 31;
  const int h = lane >> 5;
  const int bi = blockIdx.x;   // 0..63
  const int s = blockIdx.y;    // 0..7
  const bool lo = (bi < 32);   // both I0, I1 < 64 -> wrap tiles exist
  // Strip split of t-range: lo: t in [0..65] (66 = 9+9+8*6); hi: [0..64] (9+8*7).
  int t0, nt;
  if (lo) { nt = (s < 2) ? 9 : 8; t0 = (s < 2) ? 9 * s : 18 + (s - 2) * 8; }
  else    { nt = (s == 0) ? 9 : 8; t0 = (s == 0) ? 0 : 9 + (s - 1) * 8; }
  const int tmax_g0 = lo ? 64 : 63;  // g0 active iff t <= tmax_g0
  const int tmax_g1 = lo ? 65 : 64;  // g1 active iff 1 <= t <= tmax_g1
  const char* Xb = (const char*)Xn8;

  // Chunk c = rt*8 + kb*2 + hh: lane holds M[rt*32+m32][kb*64+h*32+hh*16 ..+15].
#define STAGE(base_row, dst)                                                      \
  for (int c = wave; c < 32; c += 8) {                                            \
    const int rt = c >> 3, kb = (c >> 1) & 3, hh = c & 1;                         \
    const size_t gofs =                                                           \
        (size_t)((base_row) + rt * 32 + m32) * KDIM + kb * 64 + h * 32 + hh * 16; \
    __builtin_amdgcn_global_load_lds((global_cvoid_t*)(Xb + gofs),                \
                                     (lds_void_t*)((dst) + c * 1024), 16, 0, 0);  \
  }

  STAGE(bi * 256, buf0);        // A rows of tile I0
  STAGE(bi * 256 + 128, buf1);  // A rows of tile I1
  __syncthreads();              // A landed

  // A fragments -> registers: this wave's 32 rows (group g), full K (32 VGPRs).
  frag8 areg[4];
  {
    const char* ab = g ? buf1 : buf0;
#pragma unroll
    for (int kb = 0; kb < 4; kb++) {
      const char* pa = ab + (wr2 * 8 + kb * 2) * 1024 + lane * 16;
      areg[kb].v4[0] = *(const i32x4_t*)pa;
      areg[kb].v4[1] = *(const i32x4_t*)(pa + 1024);
    }
  }
  __syncthreads();  // all waves done reading A

  STAGE(((bi * 2 + t0) & (NT - 1)) * 128, buf0);  // B(t0) -> buf0
  __syncthreads();                                // B(t0) landed

  float rs[16];
#pragma unroll
  for (int r = 0; r < 16; r++) rs[r] = 0.0f;

  for (int k = 0; k < nt; ++k) {
    const int t = t0 + k;
    const int J = (bi * 2 + t) & (NT - 1);
    char* rbuf = (k & 1) ? buf1 : buf0;  // B(k) lives here (drained at last barrier)
    char* sbuf = (k & 1) ? buf0 : buf1;  // free since last barrier

    if (k + 1 < nt) STAGE(((bi * 2 + t + 1) & (NT - 1)) * 128, sbuf);

    const bool act = g ? (t >= 1 && t <= tmax_g1) : (t <= tmax_g0);
    const bool diag = g ? (t == 1) : (t == 0);

    if (act) {
      // Two j-pairs sequentially; each pair = 2 interleaved MFMA chains (R7 shape).
#pragma unroll
      for (int jp = 0; jp < 2; ++jp) {
        f32x16_t acc[2];
        acc[0] = (f32x16_t)0.0f;
        acc[1] = (f32x16_t)0.0f;
#pragma unroll
        for (int kb = 0; kb < 4; ++kb) {
          frag8 bf[2];
#pragma unroll
          for (int j = 0; j < 2; j++) {
            const char* pb = rbuf + ((jp * 2 + j) * 8 + kb * 2) * 1024 + lane * 16;
            bf[j].v4[0] = *(const i32x4_t*)pb;
            bf[j].v4[1] = *(const i32x4_t*)(pb + 1024);
          }
#pragma unroll
          for (int j = 0; j < 2; j++)
            acc[j] = __builtin_amdgcn_mfma_scale_f32_32x32x64_f8f6f4(
                areg[kb].v8, bf[j].v8, acc[j], 0, 0, 0, 127, 0, 127);
        }
        // e = exp2(sim_scaled) = exp(5*sim). rowsums in regs; colsums scattered.
        // C/D: col = m32 (within j-subtile), row = (r&3) + 8*(r>>2) + 4*h.
        float c0 = 0.0f, c1 = 0.0f;
#pragma unroll
        for (int r = 0; r < 16; r++) {
          const float e0 = EXP2(acc[0][r]);
          const float e1 = EXP2(acc[1][r]);
          rs[r] += e0 + e1;
          c0 += e0;
          c1 += e1;
        }
        if (!diag) {  // diagonal tile: rowsum only (no double count)
          c0 += __shfl_xor(c0, 32);  // combine h halves -> 32-row col partial
          c1 += __shfl_xor(c1, 32);
          if (h == 0) {
            atomicAdd(&density[J * 128 + (jp * 2 + 0) * 32 + m32], c0);
            atomicAdd(&density[J * 128 + (jp * 2 + 1) * 32 + m32], c1);
          }
        }
      }
    }

    __syncthreads();  // B(k+1) landed; all waves done reading rbuf
  }

  // Row epilogue: reduce over 32 cols (m32), scatter; rows of tile (2bi+g).
#pragma unroll
  for (int r = 0; r < 16; r++) {
    float v = rs[r];
    v += __shfl_xor(v, 1);
    v += __shfl_xor(v, 2);
    v += __shfl_xor(v, 4);
    v += __shfl_xor(v, 8);
    v += __shfl_xor(v, 16);
    if (m32 == 0) {
      const int row = bi * 256 + g * 128 + wr2 * 32 + (r & 3) + 8 * (r >> 2) + 4 * h;
      atomicAdd(&density[row], v);
    }
  }
#undef STAGE

  // Ticket: last finished block computes the entropy (saves 2 launches).
  __syncthreads();  // all waves' atomics issued & drained; buffers free
  if (tid == 0) {
    __threadfence();
    ((volatile unsigned int*)smem)[0] = atomicAdd(ticket, 1u);
  }
  __syncthreads();
  if (((volatile unsigned int*)smem)[0] == TOTAL_BLOCKS - 1) {
    __threadfence();
    float ssum = 0.0f;
    for (int i = tid; i < NROWS; i += 512) {
      const float d = __hip_atomic_load(&density[i], __ATOMIC_RELAXED,
                                        __HIP_MEMORY_SCOPE_AGENT);
      ssum += logf(d + 1e-9f);
    }
    ssum += __shfl_xor(ssum, 1);
    ssum += __shfl_xor(ssum, 2);
    ssum += __shfl_xor(ssum, 4);
    ssum += __shfl_xor(ssum, 8);
    ssum += __shfl_xor(ssum, 16);
    ssum += __shfl_xor(ssum, 32);
    float* red = ((float*)smem) + 16;
    if (lane == 0) red[wave] = ssum;
    __syncthreads();
    if (tid == 0) {
      float tot = 0.0f;
      for (int w = 0; w < 8; w++) tot += red[w];
      out[0] = -tot / (float)NROWS;
    }
  }
}

extern "C" void kernel_launch(void* const* d_in, const int* in_sizes, int n_in,
                              void* d_out, int out_size, void* d_ws, size_t ws_size,
                              hipStream_t stream) {
  const float* X = (const float*)d_in[0];
  float* out = (float*)d_out;
  char* ws = (char*)d_ws;
  unsigned int* Xn8 = (unsigned int*)ws;
  float* density = (float*)(ws + (size_t)NROWS * KDIM);
  unsigned int* ticket = (unsigned int*)(density + NROWS);

  hipFuncSetAttribute((const void*)kde_gemm,
                      hipFuncAttributeMaxDynamicSharedMemorySize, 65536);

  kde_normalize<<<NROWS / 4, 256, 0, stream>>>(X, Xn8, density, ticket);
  kde_gemm<<<dim3(64, NSTRIP), 512, 65536, stream>>>((const unsigned char*)ws,
                                                     density, ticket, out);
}